// Round 10
// baseline (838.400 us; speedup 1.0000x reference)
//
#include <hip/hip_runtime.h>
#include <hip/hip_fp16.h>

#define NCOL 64
#define KDIM 128
#define NBB 1024        // coarse buckets (dst>>7, N<=131072)
#define CH 2048         // edges per partition chunk
#define BROWS 128       // dst rows per bucket
#define AST 68          // acc LDS row stride (16B-aligned float4, bank spread)

typedef short bf16x8 __attribute__((ext_vector_type(8)));
typedef float f32x4 __attribute__((ext_vector_type(4)));
typedef float f32x2 __attribute__((ext_vector_type(2)));

__device__ __forceinline__ unsigned short f2bf(float f) {
    unsigned int u = __float_as_uint(f);
    return (unsigned short)((u + 0x7fffu + ((u >> 16) & 1u)) >> 16);
}

// ---------------- K1: coarse bucket hist (LDS) + outcnt hist ----------------
__global__ __launch_bounds__(256) void coarse_hist(const int* __restrict__ src,
                                                   const int* __restrict__ dst,
                                                   int* __restrict__ outcnt,
                                                   int* __restrict__ bcnt, int E) {
    __shared__ int lh[NBB];
    int tid = threadIdx.x;
    for (int i = tid; i < NBB; i += 256) lh[i] = 0;
    __syncthreads();
    int i = blockIdx.x * blockDim.x + tid;
    int stride = gridDim.x * blockDim.x;
    for (int e = i; e < E; e += stride) {
        atomicAdd(&outcnt[src[e]], 1);
        atomicAdd(&lh[dst[e] >> 7], 1);
    }
    __syncthreads();
    for (int k = tid; k < NBB; k += 256) {
        int c = lh[k];
        if (c) atomicAdd(&bcnt[k], c);
    }
}

// ---------------- K2: scan 1024 bucket counts -> bbase (1025), bcur ----------------
__global__ __launch_bounds__(256) void bucket_scan(const int* __restrict__ bcnt,
                                                   int* __restrict__ bbase, int* __restrict__ bcur,
                                                   int E) {
    __shared__ int wsum[4];
    int tid = threadIdx.x, lane = tid & 63, wv = tid >> 6;
    int4 c = *(const int4*)&bcnt[tid * 4];
    int s = c.x + c.y + c.z + c.w;
    int inc = s;
#pragma unroll
    for (int off = 1; off < 64; off <<= 1) {
        int t = __shfl_up(inc, off); if (lane >= off) inc += t;
    }
    if (lane == 63) wsum[wv] = inc;
    __syncthreads();
    if (tid == 0) { int run = 0; for (int i = 0; i < 4; ++i) { int t = wsum[i]; wsum[i] = run; run += t; } }
    __syncthreads();
    int excl = wsum[wv] + inc - s;
    int b0 = excl, b1 = b0 + c.x, b2 = b1 + c.y, b3 = b2 + c.z;
    bbase[4 * tid] = b0; bbase[4 * tid + 1] = b1;
    bbase[4 * tid + 2] = b2; bbase[4 * tid + 3] = b3;
    bcur[4 * tid] = b0; bcur[4 * tid + 1] = b1;
    bcur[4 * tid + 2] = b2; bcur[4 * tid + 3] = b3;
    if (tid == 255) bbase[NBB] = excl + s;   // = E
}

// ---------------- K3: partition edges into buckets; write packed (dst&127)<<17|src ----------------
__global__ __launch_bounds__(256) void partition_kernel(
    const int* __restrict__ src, const int* __restrict__ dst,
    int* __restrict__ bcur, unsigned int* __restrict__ pk, int E) {
    __shared__ int hist[NBB];
    __shared__ int lbase[NBB];
    __shared__ int gbase[NBB];
    __shared__ int lcur[NBB];
    __shared__ uint2 sp[CH];   // 16 KB
    __shared__ int wsum[4];

    int tid = threadIdx.x, lane = tid & 63, wv = tid >> 6;
    int c0 = blockIdx.x * CH;
    int cnt = min(CH, E - c0);

    for (int i = tid; i < NBB; i += 256) hist[i] = 0;
    __syncthreads();
    for (int i = tid; i < cnt; i += 256)
        atomicAdd(&hist[dst[c0 + i] >> 7], 1);
    __syncthreads();

    // exclusive scan of 1024 bins, 4 per thread
    {
        int h0 = hist[4 * tid], h1 = hist[4 * tid + 1], h2 = hist[4 * tid + 2], h3 = hist[4 * tid + 3];
        int s = h0 + h1 + h2 + h3;
        int inc = s;
#pragma unroll
        for (int off = 1; off < 64; off <<= 1) {
            int t = __shfl_up(inc, off); if (lane >= off) inc += t;
        }
        if (lane == 63) wsum[wv] = inc;
        __syncthreads();
        if (tid == 0) { int run = 0; for (int i = 0; i < 4; ++i) { int t = wsum[i]; wsum[i] = run; run += t; } }
        __syncthreads();
        int excl = wsum[wv] + inc - s;
        lbase[4 * tid] = excl;
        lbase[4 * tid + 1] = excl + h0;
        lbase[4 * tid + 2] = excl + h0 + h1;
        lbase[4 * tid + 3] = excl + h0 + h1 + h2;
    }
    __syncthreads();

    for (int k = tid; k < NBB; k += 256) {
        int c = hist[k];
        gbase[k] = c ? atomicAdd(&bcur[k], c) : 0;
        lcur[k] = lbase[k];
    }
    __syncthreads();

    for (int i = tid; i < cnt; i += 256) {
        int s = src[c0 + i], d = dst[c0 + i];
        int p = atomicAdd(&lcur[d >> 7], 1);
        sp[p] = make_uint2((unsigned)s, (unsigned)d);
    }
    __syncthreads();

    for (int i = tid; i < cnt; i += 256) {
        uint2 p = sp[i];
        int k = (int)(p.y >> 7);
        pk[gbase[k] + (i - lbase[k])] = ((p.y & 127u) << 17) | p.x;
    }
}

// ---------------- K4: MFMA dual GEMM; h stored fp8 e4m3 col-strided ----------------
__global__ __launch_bounds__(256) void matmul_mfma(
    const float* __restrict__ feat, const float* __restrict__ W,
    const float* __restrict__ RW, const float* __restrict__ res_b,
    const int* __restrict__ outcnt,
    unsigned int* __restrict__ hb8, float* __restrict__ y, int N) {
    __shared__ bf16x8 Bf[2048];   // 32 KB
    int tid = threadIdx.x;
    for (int idx = tid; idx < 2048; idx += 256) {
        int mat = idx >> 10;
        int kc = (idx >> 8) & 3;
        int ct = (idx >> 6) & 3;
        int l = idx & 63;
        const float* Wp = mat ? RW : W;
        int kbase = kc * 32 + (l >> 4) * 8;
        int col = ct * 16 + (l & 15);
        bf16x8 t;
#pragma unroll
        for (int j = 0; j < 8; ++j)
            t[j] = (short)f2bf(Wp[(size_t)(kbase + j) * NCOL + col]);
        Bf[idx] = t;
    }
    __syncthreads();

    int lane = tid & 63;
    int wid = tid >> 6;
    int wave = blockIdx.x * 4 + wid;
    int nwaves = gridDim.x * 4;
    int ntiles = (N + 15) >> 4;
    int c16 = lane & 15, kg = lane >> 4;

    float rbv[4];
#pragma unroll
    for (int ct = 0; ct < 4; ++ct) rbv[ct] = res_b[ct * 16 + c16];

    for (int tile = wave; tile < ntiles; tile += nwaves) {
        int tb = tile << 4;
        f32x4 acch[4], accr[4];
#pragma unroll
        for (int ct = 0; ct < 4; ++ct) {
            acch[ct] = (f32x4){0.f, 0.f, 0.f, 0.f};
            accr[ct] = (f32x4){0.f, 0.f, 0.f, 0.f};
        }

        int arow = tb + c16; if (arow >= N) arow = N - 1;
        const float* fp = feat + (size_t)arow * KDIM + kg * 8;
#pragma unroll
        for (int kc = 0; kc < 4; ++kc) {
            float4 a0 = *(const float4*)(fp + kc * 32);
            float4 a1 = *(const float4*)(fp + kc * 32 + 4);
            bf16x8 af;
            af[0] = (short)f2bf(a0.x); af[1] = (short)f2bf(a0.y);
            af[2] = (short)f2bf(a0.z); af[3] = (short)f2bf(a0.w);
            af[4] = (short)f2bf(a1.x); af[5] = (short)f2bf(a1.y);
            af[6] = (short)f2bf(a1.z); af[7] = (short)f2bf(a1.w);
#pragma unroll
            for (int ct = 0; ct < 4; ++ct) {
                acch[ct] = __builtin_amdgcn_mfma_f32_16x16x32_bf16(
                    af, Bf[(kc * 4 + ct) * 64 + lane], acch[ct], 0, 0, 0);
                accr[ct] = __builtin_amdgcn_mfma_f32_16x16x32_bf16(
                    af, Bf[1024 + (kc * 4 + ct) * 64 + lane], accr[ct], 0, 0, 0);
            }
        }

        float nrm[4];
#pragma unroll
        for (int r = 0; r < 4; ++r) {
            int rw = tb + kg * 4 + r; if (rw >= N) rw = N - 1;
            nrm[r] = rsqrtf(fmaxf((float)outcnt[rw], 1.0f));
        }
#pragma unroll
        for (int r = 0; r < 4; ++r) {
            int row = tb + kg * 4 + r;
            if (row < N) {
                unsigned int p = 0;
                p = (unsigned int)__builtin_amdgcn_cvt_pk_fp8_f32(
                        acch[0][r] * nrm[r], acch[1][r] * nrm[r], (int)p, false);
                p = (unsigned int)__builtin_amdgcn_cvt_pk_fp8_f32(
                        acch[2][r] * nrm[r], acch[3][r] * nrm[r], (int)p, true);
#pragma unroll
                for (int ct = 0; ct < 4; ++ct)
                    y[(size_t)row * NCOL + ct * 16 + c16] = fmaxf(accr[ct][r] + rbv[ct], 0.0f);
                hb8[(size_t)row * 16 + c16] = p;
            }
        }
    }
}

// ---------------- K5: bucket-LDS gather + finalize ----------------
// One block per 128-dst bucket. Flat edge loop: wave = 4 edge slots x 16 lanes,
// 8 edges per slot per step (8 independent pk->hb8 chains). ds_add_f32 accumulate.
// Epilogue: coalesced float4 finalize (relu+bias+res) + BN partials.
__global__ __launch_bounds__(256) void gather_lds(
    const unsigned int* __restrict__ pk, const int* __restrict__ bbase,
    const unsigned int* __restrict__ hb8, const float* __restrict__ b,
    float* __restrict__ y, float* __restrict__ stats, int N) {
    __shared__ float acc[BROWS * AST];   // 34816 B
    __shared__ int cnt[BROWS];
    __shared__ float bnred[4][128];
    int tid = threadIdx.x, lane = tid & 63, wid = tid >> 6;
    int e4 = lane >> 4, dw = lane & 15;
    int k = blockIdx.x;
    int b0 = bbase[k];
    int b1 = bbase[k + 1];

    for (int i = tid; i < BROWS * AST; i += 256) acc[i] = 0.f;
    if (tid < BROWS) cnt[tid] = 0;
    __syncthreads();

    for (int e = b0 + wid * 32; e < b1; e += 128) {
        int eb = e + e4 * 8;
        unsigned int p[8], v[8];
#pragma unroll
        for (int u = 0; u < 8; ++u) {
            int idx = eb + u;
            p[u] = (idx < b1) ? pk[idx] : 0xFFFFFFFFu;
        }
#pragma unroll
        for (int u = 0; u < 8; ++u)
            v[u] = (p[u] != 0xFFFFFFFFu) ? hb8[(size_t)(p[u] & 0x1FFFFu) * 16 + dw] : 0u;
#pragma unroll
        for (int u = 0; u < 8; ++u) {
            if (p[u] != 0xFFFFFFFFu) {
                int dl = (int)(p[u] >> 17);
                f32x2 lo = __builtin_amdgcn_cvt_pk_f32_fp8((int)v[u], false);
                f32x2 hi = __builtin_amdgcn_cvt_pk_f32_fp8((int)v[u], true);
                float* ap = &acc[dl * AST];
                atomicAdd(&ap[dw], lo[0]);
                atomicAdd(&ap[16 + dw], lo[1]);
                atomicAdd(&ap[32 + dw], hi[0]);
                atomicAdd(&ap[48 + dw], hi[1]);
                if (dw == 0) atomicAdd(&cnt[dl], 1);
            }
        }
    }
    __syncthreads();

    // epilogue: thread handles cols q*4..q*4+3 of rows tid>>4, step 16 rows
    int q = tid & 15;
    int dst0 = k << 7;
    float4 bc = *(const float4*)&b[q * 4];
    float bs0 = 0.f, bs1 = 0.f, bs2 = 0.f, bs3 = 0.f;
    float sq0 = 0.f, sq1 = 0.f, sq2 = 0.f, sq3 = 0.f;
    for (int i = tid; i < BROWS * 16; i += 256) {
        int row = i >> 4;
        int d = dst0 + row;
        if (d < N) {
            float nd = rsqrtf(fmaxf((float)cnt[row], 1.0f));
            float4 a = *(const float4*)&acc[row * AST + q * 4];
            float* yp = &y[(size_t)d * NCOL + q * 4];
            float4 r = *(const float4*)yp;
            float4 v;
            v.x = fmaxf(a.x * nd + bc.x, 0.f) + r.x;
            v.y = fmaxf(a.y * nd + bc.y, 0.f) + r.y;
            v.z = fmaxf(a.z * nd + bc.z, 0.f) + r.z;
            v.w = fmaxf(a.w * nd + bc.w, 0.f) + r.w;
            *(float4*)yp = v;
            bs0 += v.x; bs1 += v.y; bs2 += v.z; bs3 += v.w;
            sq0 += v.x * v.x; sq1 += v.y * v.y; sq2 += v.z * v.z; sq3 += v.w * v.w;
        }
    }
    // reduce lanes {q, q+16, q+32, q+48}
#pragma unroll
    for (int off = 16; off <= 32; off <<= 1) {
        bs0 += __shfl_xor(bs0, off); bs1 += __shfl_xor(bs1, off);
        bs2 += __shfl_xor(bs2, off); bs3 += __shfl_xor(bs3, off);
        sq0 += __shfl_xor(sq0, off); sq1 += __shfl_xor(sq1, off);
        sq2 += __shfl_xor(sq2, off); sq3 += __shfl_xor(sq3, off);
    }
    if (lane < 16) {
        *(float4*)&bnred[wid][q * 4] = make_float4(bs0, bs1, bs2, bs3);
        *(float4*)&bnred[wid][64 + q * 4] = make_float4(sq0, sq1, sq2, sq3);
    }
    __syncthreads();
    if (tid < 128) {
        float v = bnred[0][tid] + bnred[1][tid] + bnred[2][tid] + bnred[3][tid];
        unsafeAtomicAdd(&stats[tid], v);
    }
}

// ---------------- K6: BN scale/shift ----------------
__global__ void bnparam_kernel(const float* __restrict__ gamma, const float* __restrict__ beta,
                               float* __restrict__ stats, float invN) {
    int c = threadIdx.x;
    float mean = stats[c] * invN;
    float var = stats[64 + c] * invN - mean * mean;
    float s = gamma[c] * rsqrtf(var + 1e-5f);
    stats[128 + c] = s;
    stats[192 + c] = beta[c] - mean * s;
}

// ---------------- K7: BN apply (in place, float4) ----------------
__global__ __launch_bounds__(256) void apply_kernel(float* __restrict__ y,
                                                    const float* __restrict__ stats, int total4) {
    int i = blockIdx.x * blockDim.x + threadIdx.x;
    int stride = gridDim.x * blockDim.x;
    float4* y4 = (float4*)y;
    for (; i < total4; i += stride) {
        float4 v = y4[i];
        int cbase = (i & 15) << 2;
        float4 s = *(const float4*)&stats[128 + cbase];
        float4 t = *(const float4*)&stats[192 + cbase];
        v.x = v.x * s.x + t.x;
        v.y = v.y * s.y + t.y;
        v.z = v.z * s.z + t.z;
        v.w = v.w * s.w + t.w;
        y4[i] = v;
    }
}

extern "C" void kernel_launch(void* const* d_in, const int* in_sizes, int n_in,
                              void* d_out, int out_size, void* d_ws, size_t ws_size,
                              hipStream_t stream) {
    const float* feat  = (const float*)d_in[0];
    const int*   src   = (const int*)d_in[1];
    const int*   dst   = (const int*)d_in[2];
    const float* W     = (const float*)d_in[3];
    const float* b     = (const float*)d_in[4];
    const float* RW    = (const float*)d_in[5];
    const float* rb    = (const float*)d_in[6];
    const float* gamma = (const float*)d_in[7];
    const float* beta  = (const float*)d_in[8];

    int N = in_sizes[0] / KDIM;
    int E = in_sizes[1];
    float* out = (float*)d_out;
    int nbuck = (N + BROWS - 1) >> 7;

    // workspace layout
    char* wsb = (char*)d_ws;
    unsigned int* hb8 = (unsigned int*)wsb;                wsb += (size_t)N * 16 * 4;
    unsigned int* pk  = (unsigned int*)wsb;                wsb += (size_t)E * 4;
    int*   outcnt   = (int*)wsb;                           wsb += (size_t)N * 4;
    float* stats    = (float*)wsb;                         wsb += 256 * 4;
    int*   bcnt     = (int*)wsb;                           wsb += NBB * 4;
    int*   bbase    = (int*)wsb;                           wsb += (NBB + 1) * 4;
    int*   bcur     = (int*)wsb;

    // zero outcnt | stats | bcnt (contiguous)
    hipMemsetAsync(outcnt, 0, ((size_t)N + 256 + NBB) * 4, stream);

    coarse_hist<<<512, 256, 0, stream>>>(src, dst, outcnt, bcnt, E);
    bucket_scan<<<1, 256, 0, stream>>>(bcnt, bbase, bcur, E);
    matmul_mfma<<<512, 256, 0, stream>>>(feat, W, RW, rb, outcnt, hb8, out, N);
    partition_kernel<<<(E + CH - 1) / CH, 256, 0, stream>>>(src, dst, bcur, pk, E);
    gather_lds<<<nbuck, 256, 0, stream>>>(pk, bbase, hb8, b, out, stats, N);
    bnparam_kernel<<<1, 64, 0, stream>>>(gamma, beta, stats, 1.0f / (float)N);
    apply_kernel<<<2048, 256, 0, stream>>>(out, stats, (N * NCOL) / 4);
}

// Round 11
// 263.833 us; speedup vs baseline: 3.1778x; 3.1778x over previous
//
#include <hip/hip_runtime.h>
#include <hip/hip_fp16.h>

#define NCOL 64
#define KDIM 128
#define NB 512          // coarse buckets (dst>>8, N<=131072)
#define CH 2048         // edges per partition chunk

typedef short bf16x8 __attribute__((ext_vector_type(8)));
typedef float f32x4 __attribute__((ext_vector_type(4)));
typedef float f32x2 __attribute__((ext_vector_type(2)));

__device__ __forceinline__ unsigned short f2bf(float f) {
    unsigned int u = __float_as_uint(f);
    return (unsigned short)((u + 0x7fffu + ((u >> 16) & 1u)) >> 16);
}

// ---------------- K1: coarse bucket hist (dst only) ----------------
__global__ __launch_bounds__(256) void coarse_hist(const int* __restrict__ dst,
                                                   int* __restrict__ bcnt, int E) {
    __shared__ int lh[NB];
    int tid = threadIdx.x;
    for (int i = tid; i < NB; i += 256) lh[i] = 0;
    __syncthreads();
    int i = blockIdx.x * blockDim.x + tid;
    int stride = gridDim.x * blockDim.x;
    for (int e = i; e < E; e += stride)
        atomicAdd(&lh[dst[e] >> 8], 1);
    __syncthreads();
    for (int k = tid; k < NB; k += 256) {
        int c = lh[k];
        if (c) atomicAdd(&bcnt[k], c);
    }
}

// ---------------- K2: scan bucket counts -> bbase, bcur ----------------
__global__ __launch_bounds__(256) void bucket_scan(const int* __restrict__ bcnt,
                                                   int* __restrict__ bbase, int* __restrict__ bcur,
                                                   int* __restrict__ row_start, int N, int E) {
    __shared__ int wsum[8];
    int tid = threadIdx.x, lane = tid & 63, wv = tid >> 6;
    int a = bcnt[tid], b = bcnt[tid + 256];
    int ia = a, ib = b;
#pragma unroll
    for (int off = 1; off < 64; off <<= 1) {
        int t = __shfl_up(ia, off); if (lane >= off) ia += t;
        int u = __shfl_up(ib, off); if (lane >= off) ib += u;
    }
    if (lane == 63) { wsum[wv] = ia; wsum[4 + wv] = ib; }
    __syncthreads();
    if (tid == 0) { int run = 0; for (int i = 0; i < 8; ++i) { int t = wsum[i]; wsum[i] = run; run += t; } }
    __syncthreads();
    int ea = wsum[wv] + ia - a;
    int eb = wsum[4 + wv] + ib - b;
    bbase[tid] = ea; bcur[tid] = ea;
    bbase[tid + 256] = eb; bcur[tid + 256] = eb;
    if (tid == 0) row_start[N] = E;
}

// ---------------- K3: partition into buckets; pk=(dst&255)<<17|src; outcnt hist ----------------
__global__ __launch_bounds__(256) void partition_kernel(
    const int* __restrict__ src, const int* __restrict__ dst,
    int* __restrict__ bcur, unsigned int* __restrict__ pk,
    int* __restrict__ outcnt, int E) {
    __shared__ int hist[NB];
    __shared__ int lbase[NB];
    __shared__ int gbase[NB];
    __shared__ int lcur[NB];
    __shared__ uint2 sp[CH];   // 16 KB
    __shared__ int wsum[8];

    int tid = threadIdx.x, lane = tid & 63, wv = tid >> 6;
    int c0 = blockIdx.x * CH;
    int cnt = min(CH, E - c0);

    for (int i = tid; i < NB; i += 256) hist[i] = 0;
    __syncthreads();
    for (int i = tid; i < cnt; i += 256)
        atomicAdd(&hist[dst[c0 + i] >> 8], 1);
    __syncthreads();

    {
        int a = hist[tid], b = hist[tid + 256];
        int ia = a, ib = b;
#pragma unroll
        for (int off = 1; off < 64; off <<= 1) {
            int t = __shfl_up(ia, off); if (lane >= off) ia += t;
            int u = __shfl_up(ib, off); if (lane >= off) ib += u;
        }
        if (lane == 63) { wsum[wv] = ia; wsum[4 + wv] = ib; }
        __syncthreads();
        if (tid == 0) { int run = 0; for (int i = 0; i < 8; ++i) { int t = wsum[i]; wsum[i] = run; run += t; } }
        __syncthreads();
        lbase[tid] = wsum[wv] + ia - a;
        lbase[tid + 256] = wsum[4 + wv] + ib - b;
    }
    __syncthreads();

    for (int k = tid; k < NB; k += 256) {
        int c = hist[k];
        gbase[k] = c ? atomicAdd(&bcur[k], c) : 0;
        lcur[k] = lbase[k];
    }
    __syncthreads();

    for (int i = tid; i < cnt; i += 256) {
        int s = src[c0 + i], d = dst[c0 + i];
        atomicAdd(&outcnt[s], 1);
        int p = atomicAdd(&lcur[d >> 8], 1);
        sp[p] = make_uint2((unsigned)s, (unsigned)d);
    }
    __syncthreads();

    for (int i = tid; i < cnt; i += 256) {
        uint2 p = sp[i];
        int k = (int)(p.y >> 8);
        pk[gbase[k] + (i - lbase[k])] = ((p.y & 255u) << 17) | p.x;
    }
}

// ---------------- K4: fine counting sort within bucket (pk input) -> ssrc + row_start ----------------
__global__ __launch_bounds__(256) void fine_kernel(
    const unsigned int* __restrict__ pk, const int* __restrict__ bbase,
    int* __restrict__ row_start, int* __restrict__ ssrc, int E, int nbuck, int N) {
    __shared__ int hist[256];
    __shared__ int cur[256];
    __shared__ int wsum[4];
    int k = blockIdx.x;
    int tid = threadIdx.x, lane = tid & 63, wv = tid >> 6;
    int b0 = bbase[k];
    int b1 = (k + 1 < nbuck) ? bbase[k + 1] : E;

    hist[tid] = 0;
    __syncthreads();
    for (int i = b0 + tid; i < b1; i += 256)
        atomicAdd(&hist[pk[i] >> 17], 1);
    __syncthreads();

    int x = hist[tid], inc = x;
#pragma unroll
    for (int off = 1; off < 64; off <<= 1) {
        int t = __shfl_up(inc, off); if (lane >= off) inc += t;
    }
    if (lane == 63) wsum[wv] = inc;
    __syncthreads();
    if (tid == 0) { int run = 0; for (int i = 0; i < 4; ++i) { int t = wsum[i]; wsum[i] = run; run += t; } }
    __syncthreads();
    int excl = wsum[wv] + inc - x;

    int d = (k << 8) + tid;
    if (d < N) row_start[d] = b0 + excl;
    cur[tid] = b0 + excl;
    __syncthreads();

    for (int i = b0 + tid; i < b1; i += 256) {
        unsigned int p = pk[i];
        int pos = atomicAdd(&cur[p >> 17], 1);
        ssrc[pos] = (int)(p & 0x1FFFFu);
    }
}

// ---------------- K5: MFMA dual GEMM; h stored fp8 e4m3 col-strided; 1 tile/wave ----------------
__global__ __launch_bounds__(256) void matmul_mfma(
    const float* __restrict__ feat, const float* __restrict__ W,
    const float* __restrict__ RW, const float* __restrict__ res_b,
    const int* __restrict__ outcnt,
    unsigned int* __restrict__ hb8, float* __restrict__ y, int N) {
    __shared__ bf16x8 Bf[2048];   // 32 KB
    int tid = threadIdx.x;
    for (int idx = tid; idx < 2048; idx += 256) {
        int mat = idx >> 10;
        int kc = (idx >> 8) & 3;
        int ct = (idx >> 6) & 3;
        int l = idx & 63;
        const float* Wp = mat ? RW : W;
        int kbase = kc * 32 + (l >> 4) * 8;
        int col = ct * 16 + (l & 15);
        bf16x8 t;
#pragma unroll
        for (int j = 0; j < 8; ++j)
            t[j] = (short)f2bf(Wp[(size_t)(kbase + j) * NCOL + col]);
        Bf[idx] = t;
    }
    __syncthreads();

    int lane = tid & 63;
    int wid = tid >> 6;
    int ntiles = (N + 15) >> 4;
    int tile = blockIdx.x * 4 + wid;
    if (tile >= ntiles) return;
    int c16 = lane & 15, kg = lane >> 4;

    float rbv[4];
#pragma unroll
    for (int ct = 0; ct < 4; ++ct) rbv[ct] = res_b[ct * 16 + c16];

    int tb = tile << 4;
    f32x4 acch[4], accr[4];
#pragma unroll
    for (int ct = 0; ct < 4; ++ct) {
        acch[ct] = (f32x4){0.f, 0.f, 0.f, 0.f};
        accr[ct] = (f32x4){0.f, 0.f, 0.f, 0.f};
    }

    int arow = tb + c16; if (arow >= N) arow = N - 1;
    const float* fp = feat + (size_t)arow * KDIM + kg * 8;
#pragma unroll
    for (int kc = 0; kc < 4; ++kc) {
        float4 a0 = *(const float4*)(fp + kc * 32);
        float4 a1 = *(const float4*)(fp + kc * 32 + 4);
        bf16x8 af;
        af[0] = (short)f2bf(a0.x); af[1] = (short)f2bf(a0.y);
        af[2] = (short)f2bf(a0.z); af[3] = (short)f2bf(a0.w);
        af[4] = (short)f2bf(a1.x); af[5] = (short)f2bf(a1.y);
        af[6] = (short)f2bf(a1.z); af[7] = (short)f2bf(a1.w);
#pragma unroll
        for (int ct = 0; ct < 4; ++ct) {
            acch[ct] = __builtin_amdgcn_mfma_f32_16x16x32_bf16(
                af, Bf[(kc * 4 + ct) * 64 + lane], acch[ct], 0, 0, 0);
            accr[ct] = __builtin_amdgcn_mfma_f32_16x16x32_bf16(
                af, Bf[1024 + (kc * 4 + ct) * 64 + lane], accr[ct], 0, 0, 0);
        }
    }

    float nrm[4];
#pragma unroll
    for (int r = 0; r < 4; ++r) {
        int rw = tb + kg * 4 + r; if (rw >= N) rw = N - 1;
        nrm[r] = rsqrtf(fmaxf((float)outcnt[rw], 1.0f));
    }
#pragma unroll
    for (int r = 0; r < 4; ++r) {
        int row = tb + kg * 4 + r;
        if (row < N) {
            unsigned int p = 0;
            p = (unsigned int)__builtin_amdgcn_cvt_pk_fp8_f32(
                    acch[0][r] * nrm[r], acch[1][r] * nrm[r], (int)p, false);
            p = (unsigned int)__builtin_amdgcn_cvt_pk_fp8_f32(
                    acch[2][r] * nrm[r], acch[3][r] * nrm[r], (int)p, true);
#pragma unroll
            for (int ct = 0; ct < 4; ++ct)
                y[(size_t)row * NCOL + ct * 16 + c16] = fmaxf(accr[ct][r] + rbv[ct], 0.0f);
            hb8[(size_t)row * 16 + c16] = p;
        }
    }
}

// ---------------- gather edge-step: 16 edges of one row per invocation ----------------
// lane: e4 = lane>>4 (edge slot 0..3), dw = lane&15 (dword of 64B fp8 row).
#define GATHER_ROW_STEP(eBase, eEnd, A0, A1, A2, A3)                                   \
    {                                                                                   \
        int e0 = (eBase) + e4, e1 = e0 + 4, e2 = e0 + 8, e3 = e0 + 12;                  \
        int i0 = (e0 < (eEnd)) ? ssrc[e0] : -1;                                         \
        int i1 = (e1 < (eEnd)) ? ssrc[e1] : -1;                                         \
        int i2 = (e2 < (eEnd)) ? ssrc[e2] : -1;                                         \
        int i3 = (e3 < (eEnd)) ? ssrc[e3] : -1;                                         \
        unsigned int v0 = (i0 >= 0) ? hb8[(size_t)i0 * 16 + dw] : 0u;                   \
        unsigned int v1 = (i1 >= 0) ? hb8[(size_t)i1 * 16 + dw] : 0u;                   \
        unsigned int v2 = (i2 >= 0) ? hb8[(size_t)i2 * 16 + dw] : 0u;                   \
        unsigned int v3 = (i3 >= 0) ? hb8[(size_t)i3 * 16 + dw] : 0u;                   \
        f32x2 l0 = __builtin_amdgcn_cvt_pk_f32_fp8((int)v0, false);                     \
        f32x2 h0 = __builtin_amdgcn_cvt_pk_f32_fp8((int)v0, true);                      \
        f32x2 l1 = __builtin_amdgcn_cvt_pk_f32_fp8((int)v1, false);                     \
        f32x2 h1 = __builtin_amdgcn_cvt_pk_f32_fp8((int)v1, true);                      \
        f32x2 l2 = __builtin_amdgcn_cvt_pk_f32_fp8((int)v2, false);                     \
        f32x2 h2 = __builtin_amdgcn_cvt_pk_f32_fp8((int)v2, true);                      \
        f32x2 l3 = __builtin_amdgcn_cvt_pk_f32_fp8((int)v3, false);                     \
        f32x2 h3 = __builtin_amdgcn_cvt_pk_f32_fp8((int)v3, true);                      \
        A0 += (l0[0] + l1[0]) + (l2[0] + l3[0]);                                        \
        A1 += (l0[1] + l1[1]) + (l2[1] + l3[1]);                                        \
        A2 += (h0[0] + h1[0]) + (h2[0] + h3[0]);                                        \
        A3 += (h0[1] + h1[1]) + (h2[1] + h3[1]);                                        \
    }

// ---------------- K6: single-pass gather, 16-deep MLP, full-wave epilogue ----------------
__global__ __launch_bounds__(256) void gather_kernel(
    const int* __restrict__ row_start, const int* __restrict__ ssrc,
    const unsigned int* __restrict__ hb8, const float* __restrict__ b,
    float* __restrict__ y, float* __restrict__ stats, int N) {
    int tid = threadIdx.x, lane = tid & 63, wid = tid >> 6;
    int e4 = lane >> 4, dw = lane & 15;
    int rowSel = e4 >> 1;
    int colLo = ((e4 & 1) << 5) + dw;      // {dw, 32+dw}
    int wave = blockIdx.x * 4 + wid;
    int nwaves = gridDim.x * 4;

    float bcLo = b[colLo], bcHi = b[colLo + 16];
    float bnLo = 0.f, bnHi = 0.f, bnsqLo = 0.f, bnsqHi = 0.f;

    for (int d0 = wave * 2; d0 < N; d0 += 2 * nwaves) {
        int d1 = d0 + 1;
        int a0 = row_start[d0], a1 = row_start[d0 + 1];
        int b0e = 0, b1e = 0;
        if (d1 < N) { b0e = a1; b1e = row_start[d1 + 1]; }

        float A0 = 0.f, A1 = 0.f, A2 = 0.f, A3 = 0.f;
        float B0 = 0.f, B1 = 0.f, B2 = 0.f, B3 = 0.f;
        int nit = max((a1 - a0 + 15) >> 4, (b1e - b0e + 15) >> 4);
        for (int it = 0; it < nit; ++it) {
            GATHER_ROW_STEP(a0 + it * 16, a1, A0, A1, A2, A3)
            GATHER_ROW_STEP(b0e + it * 16, b1e, B0, B1, B2, B3)
        }

#pragma unroll
        for (int off = 16; off <= 32; off <<= 1) {
            A0 += __shfl_xor(A0, off); A1 += __shfl_xor(A1, off);
            A2 += __shfl_xor(A2, off); A3 += __shfl_xor(A3, off);
            B0 += __shfl_xor(B0, off); B1 += __shfl_xor(B1, off);
            B2 += __shfl_xor(B2, off); B3 += __shfl_xor(B3, off);
        }

        int dd = d0 + rowSel;
        if (dd < N) {
            int deg = rowSel ? (b1e - b0e) : (a1 - a0);
            float nd = rsqrtf(fmaxf((float)deg, 1.0f));
            float vLo = rowSel ? ((e4 & 1) ? B2 : B0) : ((e4 & 1) ? A2 : A0);
            float vHi = rowSel ? ((e4 & 1) ? B3 : B1) : ((e4 & 1) ? A3 : A1);
            float* yp = &y[(size_t)dd * NCOL + colLo];
            float v0 = fmaxf(vLo * nd + bcLo, 0.f) + yp[0];
            float v1 = fmaxf(vHi * nd + bcHi, 0.f) + yp[16];
            yp[0] = v0;
            yp[16] = v1;
            bnLo += v0; bnsqLo += v0 * v0;
            bnHi += v1; bnsqHi += v1 * v1;
        }
    }

    bnLo += __shfl_xor(bnLo, 32); bnsqLo += __shfl_xor(bnsqLo, 32);
    bnHi += __shfl_xor(bnHi, 32); bnsqHi += __shfl_xor(bnsqHi, 32);

    __shared__ float bnred[4][128];
    if (lane < 32) {
        bnred[wid][colLo] = bnLo;
        bnred[wid][colLo + 16] = bnHi;
        bnred[wid][64 + colLo] = bnsqLo;
        bnred[wid][64 + colLo + 16] = bnsqHi;
    }
    __syncthreads();
    if (tid < 128) {
        float v = bnred[0][tid] + bnred[1][tid] + bnred[2][tid] + bnred[3][tid];
        unsafeAtomicAdd(&stats[tid], v);
    }
}

// ---------------- K7: BN apply (params computed in-block, in place, float4) ----------------
__global__ __launch_bounds__(256) void apply_kernel(float* __restrict__ y,
                                                    const float* __restrict__ stats,
                                                    const float* __restrict__ gamma,
                                                    const float* __restrict__ beta,
                                                    float invN, int total4) {
    __shared__ float sc[64], sh[64];
    int tid = threadIdx.x;
    if (tid < 64) {
        float mean = stats[tid] * invN;
        float var = stats[64 + tid] * invN - mean * mean;
        float s = gamma[tid] * rsqrtf(var + 1e-5f);
        sc[tid] = s;
        sh[tid] = beta[tid] - mean * s;
    }
    __syncthreads();
    int i = blockIdx.x * blockDim.x + tid;
    int stride = gridDim.x * blockDim.x;
    float4* y4 = (float4*)y;
    for (; i < total4; i += stride) {
        float4 v = y4[i];
        int cbase = (i & 15) << 2;
        float4 s = *(const float4*)&sc[cbase];
        float4 t = *(const float4*)&sh[cbase];
        v.x = v.x * s.x + t.x;
        v.y = v.y * s.y + t.y;
        v.z = v.z * s.z + t.z;
        v.w = v.w * s.w + t.w;
        y4[i] = v;
    }
}

extern "C" void kernel_launch(void* const* d_in, const int* in_sizes, int n_in,
                              void* d_out, int out_size, void* d_ws, size_t ws_size,
                              hipStream_t stream) {
    const float* feat  = (const float*)d_in[0];
    const int*   src   = (const int*)d_in[1];
    const int*   dst   = (const int*)d_in[2];
    const float* W     = (const float*)d_in[3];
    const float* b     = (const float*)d_in[4];
    const float* RW    = (const float*)d_in[5];
    const float* rb    = (const float*)d_in[6];
    const float* gamma = (const float*)d_in[7];
    const float* beta  = (const float*)d_in[8];

    int N = in_sizes[0] / KDIM;
    int E = in_sizes[1];
    float* out = (float*)d_out;
    int nbuck = (N + 255) >> 8;   // assumes N <= 131072

    // workspace layout
    char* wsb = (char*)d_ws;
    unsigned int* hb8 = (unsigned int*)wsb;                wsb += (size_t)N * 16 * 4;
    unsigned int* pk  = (unsigned int*)wsb;                wsb += (size_t)E * 4;
    int*   ssrc     = (int*)wsb;                           wsb += (size_t)E * 4;
    int*   row_start= (int*)wsb;                           wsb += (size_t)(N + 1) * 4;
    int*   outcnt   = (int*)wsb;                           wsb += (size_t)N * 4;
    float* stats    = (float*)wsb;                         wsb += 256 * 4;
    int*   bcnt     = (int*)wsb;                           wsb += NB * 4;
    int*   bbase    = (int*)wsb;                           wsb += NB * 4;
    int*   bcur     = (int*)wsb;

    // zero outcnt | stats | bcnt (contiguous)
    hipMemsetAsync(outcnt, 0, ((size_t)N + 256 + NB) * 4, stream);

    coarse_hist<<<512, 256, 0, stream>>>(dst, bcnt, E);
    bucket_scan<<<1, 256, 0, stream>>>(bcnt, bbase, bcur, row_start, N, E);
    partition_kernel<<<(E + CH - 1) / CH, 256, 0, stream>>>(src, dst, bcur, pk, outcnt, E);
    matmul_mfma<<<(((N + 15) >> 4) + 3) / 4, 256, 0, stream>>>(feat, W, RW, rb, outcnt, hb8, out, N);
    fine_kernel<<<nbuck, 256, 0, stream>>>(pk, bbase, row_start, ssrc, E, nbuck, N);
    gather_kernel<<<2048, 256, 0, stream>>>(row_start, ssrc, hb8, b, out, stats, N);
    apply_kernel<<<2048, 256, 0, stream>>>(out, stats, gamma, beta, 1.0f / (float)N, (N * NCOL) / 4);
}

// Round 12
// 239.054 us; speedup vs baseline: 3.5071x; 1.1037x over previous
//
#include <hip/hip_runtime.h>
#include <hip/hip_fp16.h>

#define NCOL 64
#define KDIM 128
#define NB 512          // coarse buckets (dst>>8, N<=131072)
#define CH 4096         // edges per chunk

typedef short bf16x8 __attribute__((ext_vector_type(8)));
typedef float f32x4 __attribute__((ext_vector_type(4)));
typedef float f32x2 __attribute__((ext_vector_type(2)));

__device__ __forceinline__ unsigned short f2bf(float f) {
    unsigned int u = __float_as_uint(f);
    return (unsigned short)((u + 0x7fffu + ((u >> 16) & 1u)) >> 16);
}

// ---------------- K1: per-chunk 512-bin hist -> gh[c][k]; outcnt + bcnt fire-and-forget ----------------
__global__ __launch_bounds__(512) void hist_kernel(const int* __restrict__ src,
                                                   const int* __restrict__ dst,
                                                   int* __restrict__ outcnt,
                                                   int* __restrict__ bcnt,
                                                   int* __restrict__ gh, int E) {
    __shared__ int lh[NB];
    int tid = threadIdx.x;
    int c = blockIdx.x;
    if (tid < NB) lh[tid] = 0;
    __syncthreads();
    int c0 = c * CH;
    int cnt = min(CH, E - c0);
    for (int i = tid; i < cnt; i += 512) {
        atomicAdd(&outcnt[src[c0 + i]], 1);
        atomicAdd(&lh[dst[c0 + i] >> 8], 1);
    }
    __syncthreads();
    if (tid < NB) {
        int v = lh[tid];
        gh[(size_t)c * NB + tid] = v;
        if (v) atomicAdd(&bcnt[tid], v);
    }
}

// ---------------- K2: scan 512 bucket totals -> bbase ----------------
__global__ __launch_bounds__(256) void bucket_scan(const int* __restrict__ bcnt,
                                                   int* __restrict__ bbase,
                                                   int* __restrict__ row_start, int N, int E) {
    __shared__ int wsum[8];
    int tid = threadIdx.x, lane = tid & 63, wv = tid >> 6;
    int a = bcnt[tid], b = bcnt[tid + 256];
    int ia = a, ib = b;
#pragma unroll
    for (int off = 1; off < 64; off <<= 1) {
        int t = __shfl_up(ia, off); if (lane >= off) ia += t;
        int u = __shfl_up(ib, off); if (lane >= off) ib += u;
    }
    if (lane == 63) { wsum[wv] = ia; wsum[4 + wv] = ib; }
    __syncthreads();
    if (tid == 0) { int run = 0; for (int i = 0; i < 8; ++i) { int t = wsum[i]; wsum[i] = run; run += t; } }
    __syncthreads();
    bbase[tid] = wsum[wv] + ia - a;
    bbase[tid + 256] = wsum[4 + wv] + ib - b;
    if (tid == 0) row_start[N] = E;
}

// ---------------- K3: per-bucket exclusive scan over chunks (in place), + bbase ----------------
__global__ __launch_bounds__(256) void chunk_scan(int* __restrict__ gh,
                                                  const int* __restrict__ bbase, int nchunks) {
    __shared__ int wsum[4];
    __shared__ int carry_s, tot_s;
    int k = blockIdx.x;
    int tid = threadIdx.x, lane = tid & 63, wv = tid >> 6;
    if (tid == 0) carry_s = bbase[k];
    __syncthreads();
    for (int t0 = 0; t0 < nchunks; t0 += 256) {
        int c = t0 + tid;
        int x = (c < nchunks) ? gh[(size_t)c * NB + k] : 0;
        int inc = x;
#pragma unroll
        for (int off = 1; off < 64; off <<= 1) {
            int t = __shfl_up(inc, off); if (lane >= off) inc += t;
        }
        if (lane == 63) wsum[wv] = inc;
        __syncthreads();
        if (tid == 0) {
            int run = 0;
            for (int i = 0; i < 4; ++i) { int t = wsum[i]; wsum[i] = run; run += t; }
            tot_s = run;
        }
        __syncthreads();
        int excl = carry_s + wsum[wv] + inc - x;
        if (c < nchunks) gh[(size_t)c * NB + k] = excl;
        __syncthreads();
        if (tid == 0) carry_s += tot_s;
        __syncthreads();
    }
}

// ---------------- K4: scatter chunk edges to pk via precomputed bases (LDS cursors) ----------------
__global__ __launch_bounds__(512) void scatter_pk(const int* __restrict__ src,
                                                  const int* __restrict__ dst,
                                                  const int* __restrict__ gh,
                                                  unsigned int* __restrict__ pk, int E) {
    __shared__ int lcur[NB];
    int tid = threadIdx.x;
    int c = blockIdx.x;
    if (tid < NB) lcur[tid] = gh[(size_t)c * NB + tid];
    __syncthreads();
    int c0 = c * CH;
    int cnt = min(CH, E - c0);
    for (int i = tid; i < cnt; i += 512) {
        int s = src[c0 + i], d = dst[c0 + i];
        int pos = atomicAdd(&lcur[d >> 8], 1);
        pk[pos] = ((unsigned)(d & 255) << 17) | (unsigned)s;
    }
}

// ---------------- K5: fine counting sort within bucket (pk input) -> ssrc + row_start ----------------
__global__ __launch_bounds__(256) void fine_kernel(
    const unsigned int* __restrict__ pk, const int* __restrict__ bbase,
    int* __restrict__ row_start, int* __restrict__ ssrc, int E, int nbuck, int N) {
    __shared__ int hist[256];
    __shared__ int cur[256];
    __shared__ int wsum[4];
    int k = blockIdx.x;
    int tid = threadIdx.x, lane = tid & 63, wv = tid >> 6;
    int b0 = bbase[k];
    int b1 = (k + 1 < nbuck) ? bbase[k + 1] : E;

    hist[tid] = 0;
    __syncthreads();
    for (int i = b0 + tid; i < b1; i += 256)
        atomicAdd(&hist[pk[i] >> 17], 1);
    __syncthreads();

    int x = hist[tid], inc = x;
#pragma unroll
    for (int off = 1; off < 64; off <<= 1) {
        int t = __shfl_up(inc, off); if (lane >= off) inc += t;
    }
    if (lane == 63) wsum[wv] = inc;
    __syncthreads();
    if (tid == 0) { int run = 0; for (int i = 0; i < 4; ++i) { int t = wsum[i]; wsum[i] = run; run += t; } }
    __syncthreads();
    int excl = wsum[wv] + inc - x;

    int d = (k << 8) + tid;
    if (d < N) row_start[d] = b0 + excl;
    cur[tid] = b0 + excl;
    __syncthreads();

    for (int i = b0 + tid; i < b1; i += 256) {
        unsigned int p = pk[i];
        int pos = atomicAdd(&cur[p >> 17], 1);
        ssrc[pos] = (int)(p & 0x1FFFFu);
    }
}

// ---------------- K6: MFMA dual GEMM; h stored fp8 e4m3 col-strided; 1 tile/wave ----------------
__global__ __launch_bounds__(256) void matmul_mfma(
    const float* __restrict__ feat, const float* __restrict__ W,
    const float* __restrict__ RW, const float* __restrict__ res_b,
    const int* __restrict__ outcnt,
    unsigned int* __restrict__ hb8, float* __restrict__ y, int N) {
    __shared__ bf16x8 Bf[2048];   // 32 KB
    int tid = threadIdx.x;
    for (int idx = tid; idx < 2048; idx += 256) {
        int mat = idx >> 10;
        int kc = (idx >> 8) & 3;
        int ct = (idx >> 6) & 3;
        int l = idx & 63;
        const float* Wp = mat ? RW : W;
        int kbase = kc * 32 + (l >> 4) * 8;
        int col = ct * 16 + (l & 15);
        bf16x8 t;
#pragma unroll
        for (int j = 0; j < 8; ++j)
            t[j] = (short)f2bf(Wp[(size_t)(kbase + j) * NCOL + col]);
        Bf[idx] = t;
    }
    __syncthreads();

    int lane = tid & 63;
    int wid = tid >> 6;
    int ntiles = (N + 15) >> 4;
    int tile = blockIdx.x * 4 + wid;
    if (tile >= ntiles) return;
    int c16 = lane & 15, kg = lane >> 4;

    float rbv[4];
#pragma unroll
    for (int ct = 0; ct < 4; ++ct) rbv[ct] = res_b[ct * 16 + c16];

    int tb = tile << 4;
    f32x4 acch[4], accr[4];
#pragma unroll
    for (int ct = 0; ct < 4; ++ct) {
        acch[ct] = (f32x4){0.f, 0.f, 0.f, 0.f};
        accr[ct] = (f32x4){0.f, 0.f, 0.f, 0.f};
    }

    int arow = tb + c16; if (arow >= N) arow = N - 1;
    const float* fp = feat + (size_t)arow * KDIM + kg * 8;
#pragma unroll
    for (int kc = 0; kc < 4; ++kc) {
        float4 a0 = *(const float4*)(fp + kc * 32);
        float4 a1 = *(const float4*)(fp + kc * 32 + 4);
        bf16x8 af;
        af[0] = (short)f2bf(a0.x); af[1] = (short)f2bf(a0.y);
        af[2] = (short)f2bf(a0.z); af[3] = (short)f2bf(a0.w);
        af[4] = (short)f2bf(a1.x); af[5] = (short)f2bf(a1.y);
        af[6] = (short)f2bf(a1.z); af[7] = (short)f2bf(a1.w);
#pragma unroll
        for (int ct = 0; ct < 4; ++ct) {
            acch[ct] = __builtin_amdgcn_mfma_f32_16x16x32_bf16(
                af, Bf[(kc * 4 + ct) * 64 + lane], acch[ct], 0, 0, 0);
            accr[ct] = __builtin_amdgcn_mfma_f32_16x16x32_bf16(
                af, Bf[1024 + (kc * 4 + ct) * 64 + lane], accr[ct], 0, 0, 0);
        }
    }

    float nrm[4];
#pragma unroll
    for (int r = 0; r < 4; ++r) {
        int rw = tb + kg * 4 + r; if (rw >= N) rw = N - 1;
        nrm[r] = rsqrtf(fmaxf((float)outcnt[rw], 1.0f));
    }
#pragma unroll
    for (int r = 0; r < 4; ++r) {
        int row = tb + kg * 4 + r;
        if (row < N) {
            unsigned int p = 0;
            p = (unsigned int)__builtin_amdgcn_cvt_pk_fp8_f32(
                    acch[0][r] * nrm[r], acch[1][r] * nrm[r], (int)p, false);
            p = (unsigned int)__builtin_amdgcn_cvt_pk_fp8_f32(
                    acch[2][r] * nrm[r], acch[3][r] * nrm[r], (int)p, true);
#pragma unroll
            for (int ct = 0; ct < 4; ++ct)
                y[(size_t)row * NCOL + ct * 16 + c16] = fmaxf(accr[ct][r] + rbv[ct], 0.0f);
            hb8[(size_t)row * 16 + c16] = p;
        }
    }
}

// ---------------- gather edge-step: 16 edges of one row per invocation ----------------
#define GATHER_ROW_STEP(eBase, eEnd, A0, A1, A2, A3)                                   \
    {                                                                                   \
        int e0 = (eBase) + e4, e1 = e0 + 4, e2 = e0 + 8, e3 = e0 + 12;                  \
        int i0 = (e0 < (eEnd)) ? ssrc[e0] : -1;                                         \
        int i1 = (e1 < (eEnd)) ? ssrc[e1] : -1;                                         \
        int i2 = (e2 < (eEnd)) ? ssrc[e2] : -1;                                         \
        int i3 = (e3 < (eEnd)) ? ssrc[e3] : -1;                                         \
        unsigned int v0 = (i0 >= 0) ? hb8[(size_t)i0 * 16 + dw] : 0u;                   \
        unsigned int v1 = (i1 >= 0) ? hb8[(size_t)i1 * 16 + dw] : 0u;                   \
        unsigned int v2 = (i2 >= 0) ? hb8[(size_t)i2 * 16 + dw] : 0u;                   \
        unsigned int v3 = (i3 >= 0) ? hb8[(size_t)i3 * 16 + dw] : 0u;                   \
        f32x2 l0 = __builtin_amdgcn_cvt_pk_f32_fp8((int)v0, false);                     \
        f32x2 h0 = __builtin_amdgcn_cvt_pk_f32_fp8((int)v0, true);                      \
        f32x2 l1 = __builtin_amdgcn_cvt_pk_f32_fp8((int)v1, false);                     \
        f32x2 h1 = __builtin_amdgcn_cvt_pk_f32_fp8((int)v1, true);                      \
        f32x2 l2 = __builtin_amdgcn_cvt_pk_f32_fp8((int)v2, false);                     \
        f32x2 h2 = __builtin_amdgcn_cvt_pk_f32_fp8((int)v2, true);                      \
        f32x2 l3 = __builtin_amdgcn_cvt_pk_f32_fp8((int)v3, false);                     \
        f32x2 h3 = __builtin_amdgcn_cvt_pk_f32_fp8((int)v3, true);                      \
        A0 += (l0[0] + l1[0]) + (l2[0] + l3[0]);                                        \
        A1 += (l0[1] + l1[1]) + (l2[1] + l3[1]);                                        \
        A2 += (h0[0] + h1[0]) + (h2[0] + h3[0]);                                        \
        A3 += (h0[1] + h1[1]) + (h2[1] + h3[1]);                                        \
    }

// ---------------- K7: single-pass gather, 16-deep MLP, full-wave epilogue ----------------
__global__ __launch_bounds__(256) void gather_kernel(
    const int* __restrict__ row_start, const int* __restrict__ ssrc,
    const unsigned int* __restrict__ hb8, const float* __restrict__ b,
    float* __restrict__ y, float* __restrict__ stats, int N) {
    int tid = threadIdx.x, lane = tid & 63, wid = tid >> 6;
    int e4 = lane >> 4, dw = lane & 15;
    int rowSel = e4 >> 1;
    int colLo = ((e4 & 1) << 5) + dw;      // {dw, 32+dw}
    int wave = blockIdx.x * 4 + wid;
    int nwaves = gridDim.x * 4;

    float bcLo = b[colLo], bcHi = b[colLo + 16];
    float bnLo = 0.f, bnHi = 0.f, bnsqLo = 0.f, bnsqHi = 0.f;

    for (int d0 = wave * 2; d0 < N; d0 += 2 * nwaves) {
        int d1 = d0 + 1;
        int a0 = row_start[d0], a1 = row_start[d0 + 1];
        int b0e = 0, b1e = 0;
        if (d1 < N) { b0e = a1; b1e = row_start[d1 + 1]; }

        float A0 = 0.f, A1 = 0.f, A2 = 0.f, A3 = 0.f;
        float B0 = 0.f, B1 = 0.f, B2 = 0.f, B3 = 0.f;
        int nit = max((a1 - a0 + 15) >> 4, (b1e - b0e + 15) >> 4);
        for (int it = 0; it < nit; ++it) {
            GATHER_ROW_STEP(a0 + it * 16, a1, A0, A1, A2, A3)
            GATHER_ROW_STEP(b0e + it * 16, b1e, B0, B1, B2, B3)
        }

#pragma unroll
        for (int off = 16; off <= 32; off <<= 1) {
            A0 += __shfl_xor(A0, off); A1 += __shfl_xor(A1, off);
            A2 += __shfl_xor(A2, off); A3 += __shfl_xor(A3, off);
            B0 += __shfl_xor(B0, off); B1 += __shfl_xor(B1, off);
            B2 += __shfl_xor(B2, off); B3 += __shfl_xor(B3, off);
        }

        int dd = d0 + rowSel;
        if (dd < N) {
            int deg = rowSel ? (b1e - b0e) : (a1 - a0);
            float nd = rsqrtf(fmaxf((float)deg, 1.0f));
            float vLo = rowSel ? ((e4 & 1) ? B2 : B0) : ((e4 & 1) ? A2 : A0);
            float vHi = rowSel ? ((e4 & 1) ? B3 : B1) : ((e4 & 1) ? A3 : A1);
            float* yp = &y[(size_t)dd * NCOL + colLo];
            float v0 = fmaxf(vLo * nd + bcLo, 0.f) + yp[0];
            float v1 = fmaxf(vHi * nd + bcHi, 0.f) + yp[16];
            yp[0] = v0;
            yp[16] = v1;
            bnLo += v0; bnsqLo += v0 * v0;
            bnHi += v1; bnsqHi += v1 * v1;
        }
    }

    bnLo += __shfl_xor(bnLo, 32); bnsqLo += __shfl_xor(bnsqLo, 32);
    bnHi += __shfl_xor(bnHi, 32); bnsqHi += __shfl_xor(bnsqHi, 32);

    __shared__ float bnred[4][128];
    if (lane < 32) {
        bnred[wid][colLo] = bnLo;
        bnred[wid][colLo + 16] = bnHi;
        bnred[wid][64 + colLo] = bnsqLo;
        bnred[wid][64 + colLo + 16] = bnsqHi;
    }
    __syncthreads();
    if (tid < 128) {
        float v = bnred[0][tid] + bnred[1][tid] + bnred[2][tid] + bnred[3][tid];
        unsafeAtomicAdd(&stats[tid], v);
    }
}

// ---------------- K8: BN apply (params computed in-block, in place, float4) ----------------
__global__ __launch_bounds__(256) void apply_kernel(float* __restrict__ y,
                                                    const float* __restrict__ stats,
                                                    const float* __restrict__ gamma,
                                                    const float* __restrict__ beta,
                                                    float invN, int total4) {
    __shared__ float sc[64], sh[64];
    int tid = threadIdx.x;
    if (tid < 64) {
        float mean = stats[tid] * invN;
        float var = stats[64 + tid] * invN - mean * mean;
        float s = gamma[tid] * rsqrtf(var + 1e-5f);
        sc[tid] = s;
        sh[tid] = beta[tid] - mean * s;
    }
    __syncthreads();
    int i = blockIdx.x * blockDim.x + tid;
    int stride = gridDim.x * blockDim.x;
    float4* y4 = (float4*)y;
    for (; i < total4; i += stride) {
        float4 v = y4[i];
        int cbase = (i & 15) << 2;
        float4 s = *(const float4*)&sc[cbase];
        float4 t = *(const float4*)&sh[cbase];
        v.x = v.x * s.x + t.x;
        v.y = v.y * s.y + t.y;
        v.z = v.z * s.z + t.z;
        v.w = v.w * s.w + t.w;
        y4[i] = v;
    }
}

extern "C" void kernel_launch(void* const* d_in, const int* in_sizes, int n_in,
                              void* d_out, int out_size, void* d_ws, size_t ws_size,
                              hipStream_t stream) {
    const float* feat  = (const float*)d_in[0];
    const int*   src   = (const int*)d_in[1];
    const int*   dst   = (const int*)d_in[2];
    const float* W     = (const float*)d_in[3];
    const float* b     = (const float*)d_in[4];
    const float* RW    = (const float*)d_in[5];
    const float* rb    = (const float*)d_in[6];
    const float* gamma = (const float*)d_in[7];
    const float* beta  = (const float*)d_in[8];

    int N = in_sizes[0] / KDIM;
    int E = in_sizes[1];
    float* out = (float*)d_out;
    int nbuck = (N + 255) >> 8;           // 391 for N=100000
    int nchunks = (E + CH - 1) / CH;      // 391 for E=1.6M

    // workspace layout
    char* wsb = (char*)d_ws;
    unsigned int* hb8 = (unsigned int*)wsb;                wsb += (size_t)N * 16 * 4;
    unsigned int* pk  = (unsigned int*)wsb;                wsb += (size_t)E * 4;
    int*   ssrc     = (int*)wsb;                           wsb += (size_t)E * 4;
    int*   row_start= (int*)wsb;                           wsb += (size_t)(N + 1) * 4;
    int*   outcnt   = (int*)wsb;                           wsb += (size_t)N * 4;
    float* stats    = (float*)wsb;                         wsb += 256 * 4;
    int*   bcnt     = (int*)wsb;                           wsb += NB * 4;
    int*   bbase    = (int*)wsb;                           wsb += NB * 4;
    int*   gh       = (int*)wsb;                           // nchunks*NB ints

    // zero outcnt | stats | bcnt (contiguous)
    hipMemsetAsync(outcnt, 0, ((size_t)N + 256 + NB) * 4, stream);

    hist_kernel<<<nchunks, 512, 0, stream>>>(src, dst, outcnt, bcnt, gh, E);
    bucket_scan<<<1, 256, 0, stream>>>(bcnt, bbase, row_start, N, E);
    matmul_mfma<<<(((N + 15) >> 4) + 3) / 4, 256, 0, stream>>>(feat, W, RW, rb, outcnt, hb8, out, N);
    chunk_scan<<<NB, 256, 0, stream>>>(gh, bbase, nchunks);
    scatter_pk<<<nchunks, 512, 0, stream>>>(src, dst, gh, pk, E);
    fine_kernel<<<nbuck, 256, 0, stream>>>(pk, bbase, row_start, ssrc, E, nbuck, N);
    gather_kernel<<<2048, 256, 0, stream>>>(row_start, ssrc, hb8, b, out, stats, N);
    apply_kernel<<<2048, 256, 0, stream>>>(out, stats, gamma, beta, 1.0f / (float)N, (N * NCOL) / 4);
}